// Round 1
// baseline (123.630 us; speedup 1.0000x reference)
//
#include <hip/hip_runtime.h>
#include <math.h>

#define N_OCT  32
#define N_SMP  32768
#define N_PAIR 64   // B*E = 4*16

// ---------------------------------------------------------------------------
// Kernel 1: per-(b,e) setup. Replicates the reference's fp32 arithmetic
// BIT-EXACTLY where it matters: factors = sequential fp32 cumsum of fs
// (any deviation is amplified by t<=32768 into radians of phase error).
// Also zero-inits the per-pair max accumulator (d_ws is poisoned 0xAA).
// ---------------------------------------------------------------------------
__global__ __launch_bounds__(64) void f0res_setup(
    const float* __restrict__ f0_in,
    const float* __restrict__ dec_in,
    const float* __restrict__ fs_in,
    float* __restrict__ w_out,        // [N_PAIR][N_OCT] masked angular freqs
    float* __restrict__ a_out,        // [N_PAIR][N_OCT] decay amplitudes
    unsigned* __restrict__ mx)        // [N_PAIR] max|osc| as uint bits
{
    int p = threadIdx.x;
    if (p >= N_PAIR) return;
    mx[p] = 0u;                       // abs values are >=0: uint order == float order

    const float minf   = (float)(20.0 / 11025.0);
    const float frange = (float)(3000.0 / 11025.0 - 20.0 / 11025.0);
    const float pif    = (float)3.14159265358979323846;

    float f0 = fabsf(f0_in[p]);
    float fs = fs_in[p];
    float x  = dec_in[p];

    // double sigmoid (reference applies sigmoid twice)
    float s1 = 1.0f / (1.0f + expf(-x));
    float s2 = 1.0f / (1.0f + expf(-s1));
    float d  = 0.01f + s2 * (float)(0.99 * 0.99);   // resonance_factor = 0.9801
    float ld = logf(d + 1e-12f);

    float f0p = (minf + f0 * frange) * pif;

    float fac = 0.0f, acl = 0.0f;
    for (int o = 0; o < N_OCT; ++o) {
        fac += fs;                    // sequential fp32 cumsum — must match np
        acl += ld;
        float f0s = f0p * fac;
        w_out[p * N_OCT + o] = (f0s < 1.0f) ? f0s : 0.0f;  // Nyquist mask; sin(0)=0
        a_out[p * N_OCT + o] = expf(acl);                  // d^(o+1)
    }
}

// ---------------------------------------------------------------------------
// Kernel 2: one thread per sample. phase = fl(w*t) in fp32 (bit-matches the
// np reference), then accurate sin via double mod-2pi reduction + hw v_sin.
// Writes unnormalized osc and accumulates per-pair max|osc| via atomicMax.
// ---------------------------------------------------------------------------
__global__ __launch_bounds__(256) void f0res_osc(
    const float* __restrict__ w_all,
    const float* __restrict__ a_all,
    float* __restrict__ out,
    unsigned* __restrict__ mx)
{
    __shared__ float sw[N_OCT], sa[N_OCT];
    __shared__ float wave_max[4];

    const int pair = blockIdx.x >> 7;          // 128 blocks per (b,e) pair
    const int tid  = threadIdx.x;
    if (tid < N_OCT) {
        sw[tid] = w_all[pair * N_OCT + tid];
        sa[tid] = a_all[pair * N_OCT + tid];
    }
    __syncthreads();

    const int   s  = ((blockIdx.x & 127) << 8) + tid;   // sample index in pair
    const float tf = (float)(s + 1);                    // t = 1..N_SMP, exact in fp32

    float acc = 0.0f;
#pragma unroll
    for (int o = 0; o < N_OCT; ++o) {
        float  ph = sw[o] * tf;                          // exact fp32 phase (matches ref)
        double pd = (double)ph;
        double k  = rint(pd * 1.5915494309189535e-1);    // nearest multiple of 2pi
        float  r  = (float)fma(k, -6.283185307179586, pd); // |r| <= pi, err ~1e-12
        acc = fmaf(sa[o], __sinf(r), acc);               // hw v_sin on small arg
    }

    out[pair * N_SMP + s] = acc;

    // block max of |acc| -> one global atomic per block
    float av = fabsf(acc);
#pragma unroll
    for (int m = 32; m >= 1; m >>= 1)
        av = fmaxf(av, __shfl_xor(av, m, 64));
    if ((tid & 63) == 0) wave_max[tid >> 6] = av;
    __syncthreads();
    if (tid == 0) {
        float v = fmaxf(fmaxf(wave_max[0], wave_max[1]),
                        fmaxf(wave_max[2], wave_max[3]));
        atomicMax(&mx[pair], __float_as_uint(v));
    }
}

// ---------------------------------------------------------------------------
// Kernel 3: normalize, float4-vectorized. out /= (mx + 1e-8)
// ---------------------------------------------------------------------------
__global__ __launch_bounds__(256) void f0res_norm(
    float* __restrict__ out, const unsigned* __restrict__ mx)
{
    const int pair = blockIdx.x >> 5;                   // 32 blocks per pair (8192 f4)
    const int idx  = ((blockIdx.x & 31) << 8) + threadIdx.x;
    const float m  = __uint_as_float(mx[pair]) + 1e-8f;
    float4* o4 = (float4*)(out + pair * N_SMP);
    float4 v = o4[idx];
    v.x /= m; v.y /= m; v.z /= m; v.w /= m;
    o4[idx] = v;
}

extern "C" void kernel_launch(void* const* d_in, const int* in_sizes, int n_in,
                              void* d_out, int out_size, void* d_ws, size_t ws_size,
                              hipStream_t stream) {
    const float* f0  = (const float*)d_in[0];
    const float* dec = (const float*)d_in[1];
    const float* fs  = (const float*)d_in[2];
    float* out = (float*)d_out;

    float*    w  = (float*)d_ws;                   // 64*32 floats
    float*    a  = w + N_PAIR * N_OCT;             // 64*32 floats
    unsigned* mx = (unsigned*)(a + N_PAIR * N_OCT);// 64 uints

    f0res_setup<<<1, 64, 0, stream>>>(f0, dec, fs, w, a, mx);
    f0res_osc<<<N_PAIR * 128, 256, 0, stream>>>(w, a, out, mx);
    f0res_norm<<<N_PAIR * 32, 256, 0, stream>>>(out, mx);
}

// Round 2
// 84.058 us; speedup vs baseline: 1.4708x; 1.4708x over previous
//
#include <hip/hip_runtime.h>
#include <math.h>

#define N_OCT  32
#define N_SMP  32768
#define N_PAIR 64   // B*E = 4*16

// ---------------------------------------------------------------------------
// Kernel 1: per-(b,e) setup. Replicates the reference's fp32 arithmetic with
// SEQUENTIAL fp32 cumsums (any deviation is amplified by t<=32768 into
// radians of phase error).
// ---------------------------------------------------------------------------
__global__ __launch_bounds__(64) void f0res_setup(
    const float* __restrict__ f0_in,
    const float* __restrict__ dec_in,
    const float* __restrict__ fs_in,
    float* __restrict__ w_out,        // [N_PAIR][N_OCT] masked angular freqs
    float* __restrict__ a_out)        // [N_PAIR][N_OCT] decay amplitudes
{
    int p = threadIdx.x;
    if (p >= N_PAIR) return;

    const float minf   = (float)(20.0 / 11025.0);
    const float frange = (float)(3000.0 / 11025.0 - 20.0 / 11025.0);
    const float pif    = (float)3.14159265358979323846;

    float f0 = fabsf(f0_in[p]);
    float fs = fs_in[p];
    float x  = dec_in[p];

    // double sigmoid (reference applies sigmoid twice)
    float s1 = 1.0f / (1.0f + expf(-x));
    float s2 = 1.0f / (1.0f + expf(-s1));
    float d  = 0.01f + s2 * (float)(0.99 * 0.99);   // resonance_factor = 0.9801
    float ld = logf(d + 1e-12f);

    float f0p = (minf + f0 * frange) * pif;

    float fac = 0.0f, acl = 0.0f;
    for (int o = 0; o < N_OCT; ++o) {
        fac += fs;                    // sequential fp32 cumsum — must match np
        acl += ld;
        float f0s = f0p * fac;
        w_out[p * N_OCT + o] = (f0s < 1.0f) ? f0s : 0.0f;  // Nyquist mask; sin(0)=0
        a_out[p * N_OCT + o] = expf(acl);                  // d^(o+1)
    }
}

// ---------------------------------------------------------------------------
// Kernel 2: one thread per sample. phase = fl(w*t) in fp32 (bit-matches the
// np reference). All-fp32 two-term Cody-Waite reduction to REVOLUTIONS
// (v_sin_f32 takes revolutions):
//   k   = rndne(ph * inv2pi)           (k <= 5216, exact integer)
//   rev = fma(ph, I2, fma(ph, I1, -k)) where I1+I2 = 1/2pi to ~48 bits
// error ~2e-7 rev (~1.3e-6 rad). No fp64, no per-octave LDS reads.
// Per-block max written NON-atomically to bmax[pair*128+blk].
// ---------------------------------------------------------------------------
__global__ __launch_bounds__(256) void f0res_osc(
    const float* __restrict__ w_all,
    const float* __restrict__ a_all,
    float* __restrict__ out,
    float* __restrict__ bmax)
{
    const int pair = blockIdx.x >> 7;          // 128 blocks per (b,e) pair
    const int blk  = blockIdx.x & 127;
    const int tid  = threadIdx.x;

    // hoist the 32 (w,a) pairs into registers: 16 dwordx4 loads, L2-resident
    const float4* w4 = (const float4*)(w_all + pair * N_OCT);
    const float4* a4 = (const float4*)(a_all + pair * N_OCT);
    float4 wv[8], av[8];
#pragma unroll
    for (int i = 0; i < 8; ++i) { wv[i] = w4[i]; av[i] = a4[i]; }

    const int   s  = (blk << 8) + tid;          // sample index within pair
    const float tf = (float)(s + 1);            // t = 1..N_SMP, exact in fp32

    const float INV2PI = 0.15915494309189535f;  // 1/2pi
    const float I1     = 0.159149169921875f;    // 12-bit head of 1/2pi
    const float I2     = 5.7731700203e-06f;     // 1/2pi - I1

    float acc = 0.0f;
#pragma unroll
    for (int i = 0; i < 8; ++i) {
        const float wr[4] = { wv[i].x, wv[i].y, wv[i].z, wv[i].w };
        const float ar[4] = { av[i].x, av[i].y, av[i].z, av[i].w };
#pragma unroll
        for (int j = 0; j < 4; ++j) {
            float ph  = wr[j] * tf;                    // exact fp32 phase (matches ref)
            float k   = rintf(ph * INV2PI);            // v_rndne_f32
            float t1  = fmaf(ph, I1, -k);              // |t1| <= ~0.7, 1 rounding
            float rev = fmaf(ph, I2, t1);              // phase mod 1, in revolutions
            acc = fmaf(ar[j], __builtin_amdgcn_sinf(rev), acc);
        }
    }

    out[pair * N_SMP + s] = acc;

    // block max of |acc| -> one plain store per block (no atomics, no init)
    float av_ = fabsf(acc);
#pragma unroll
    for (int m = 32; m >= 1; m >>= 1)
        av_ = fmaxf(av_, __shfl_xor(av_, m, 64));
    __shared__ float wm[4];
    if ((tid & 63) == 0) wm[tid >> 6] = av_;
    __syncthreads();
    if (tid == 0)
        bmax[pair * 128 + blk] = fmaxf(fmaxf(wm[0], wm[1]), fmaxf(wm[2], wm[3]));
}

// ---------------------------------------------------------------------------
// Kernel 3: reduce the 128 per-block maxes, then normalize (float4).
// ---------------------------------------------------------------------------
__global__ __launch_bounds__(256) void f0res_norm(
    float* __restrict__ out, const float* __restrict__ bmax)
{
    const int pair = blockIdx.x >> 5;                   // 32 blocks per pair
    const int tid  = threadIdx.x;

    float v = 0.0f;
    if (tid < 128) v = bmax[pair * 128 + tid];
#pragma unroll
    for (int m = 32; m >= 1; m >>= 1)
        v = fmaxf(v, __shfl_xor(v, m, 64));
    __shared__ float wm[4];
    if ((tid & 63) == 0) wm[tid >> 6] = v;              // waves 2,3 write 0 (harmless)
    __syncthreads();
    const float mx  = fmaxf(fmaxf(wm[0], wm[1]), fmaxf(wm[2], wm[3])) + 1e-8f;
    const float inv = 1.0f / mx;

    const int idx = ((blockIdx.x & 31) << 8) + tid;     // 256 float4 per block
    float4* o4 = (float4*)(out + pair * N_SMP);
    float4 val = o4[idx];
    val.x *= inv; val.y *= inv; val.z *= inv; val.w *= inv;
    o4[idx] = val;
}

extern "C" void kernel_launch(void* const* d_in, const int* in_sizes, int n_in,
                              void* d_out, int out_size, void* d_ws, size_t ws_size,
                              hipStream_t stream) {
    const float* f0  = (const float*)d_in[0];
    const float* dec = (const float*)d_in[1];
    const float* fs  = (const float*)d_in[2];
    float* out = (float*)d_out;

    float* w    = (float*)d_ws;                 // 64*32 floats
    float* a    = w + N_PAIR * N_OCT;           // 64*32 floats
    float* bmax = a + N_PAIR * N_OCT;           // 64*128 floats

    f0res_setup<<<1, 64, 0, stream>>>(f0, dec, fs, w, a);
    f0res_osc<<<N_PAIR * 128, 256, 0, stream>>>(w, a, out, bmax);
    f0res_norm<<<N_PAIR * 32, 256, 0, stream>>>(out, bmax);
}

// Round 3
// 78.469 us; speedup vs baseline: 1.5755x; 1.0712x over previous
//
#include <hip/hip_runtime.h>
#include <math.h>

#define N_OCT  32
#define N_SMP  32768
#define N_PAIR 64   // B*E = 4*16

// ---------------------------------------------------------------------------
// Kernel 1: per-(b,e) setup. Sequential fp32 cumsums match the reference's
// rounding sequence. Stores frequencies pre-divided by 2pi (REVOLUTIONS per
// sample) so the osc kernel needs only mul+fract+v_sin+fma per octave.
// Phase error from the w/2pi pre-rounding is ~1e-7 relative — well inside
// the 5.9e-3 fp32-phase-quantization floor observed in R1/R2.
// ---------------------------------------------------------------------------
__global__ __launch_bounds__(64) void f0res_setup(
    const float* __restrict__ f0_in,
    const float* __restrict__ dec_in,
    const float* __restrict__ fs_in,
    float* __restrict__ wrev_out,     // [N_PAIR][N_OCT] masked freqs, revolutions
    float* __restrict__ a_out)        // [N_PAIR][N_OCT] decay amplitudes
{
    int p = threadIdx.x;
    if (p >= N_PAIR) return;

    const float minf   = (float)(20.0 / 11025.0);
    const float frange = (float)(3000.0 / 11025.0 - 20.0 / 11025.0);
    const float pif    = (float)3.14159265358979323846;
    const float INV2PI = 0.15915494309189535f;

    float f0 = fabsf(f0_in[p]);
    float fs = fs_in[p];
    float x  = dec_in[p];

    // double sigmoid (reference applies sigmoid twice)
    float s1 = 1.0f / (1.0f + expf(-x));
    float s2 = 1.0f / (1.0f + expf(-s1));
    float d  = 0.01f + s2 * (float)(0.99 * 0.99);
    float ld = logf(d + 1e-12f);

    float f0p = (minf + f0 * frange) * pif;

    float fac = 0.0f, acl = 0.0f;
    for (int o = 0; o < N_OCT; ++o) {
        fac += fs;                    // sequential fp32 cumsum — must match ref
        acl += ld;
        float f0s = f0p * fac;
        wrev_out[p * N_OCT + o] = (f0s < 1.0f) ? f0s * INV2PI : 0.0f;
        a_out[p * N_OCT + o]    = expf(acl);
    }
}

// ---------------------------------------------------------------------------
// Kernel 2: 2 samples per thread, 64 blocks per pair. Per octave per sample:
//   rev = w' * t        (v_mul)
//   fr  = fract(rev)    (v_fract_f32 — exact; v_sin needs [0,1))
//   s   = v_sin(fr)     (hardware sin, input in revolutions)
//   acc = fma(a, s, acc)
// 4 VALU ops, sin-rate dominated. w'/a loads are wave-uniform -> s_loads.
// Per-block max written NON-atomically to bmax[pair*64+blk] (no init needed).
// ---------------------------------------------------------------------------
__global__ __launch_bounds__(256) void f0res_osc(
    const float* __restrict__ w_all,
    const float* __restrict__ a_all,
    float* __restrict__ out,
    float* __restrict__ bmax)
{
    const int pair = blockIdx.x >> 6;          // 64 blocks per (b,e) pair
    const int blk  = blockIdx.x & 63;
    const int tid  = threadIdx.x;

    const float4* w4 = (const float4*)(w_all + pair * N_OCT);
    const float4* a4 = (const float4*)(a_all + pair * N_OCT);
    float4 wv[8], av[8];
#pragma unroll
    for (int i = 0; i < 8; ++i) { wv[i] = w4[i]; av[i] = a4[i]; }

    const int   s0 = (blk << 9) + tid;          // this thread: s0 and s0+256
    const float t0 = (float)(s0 + 1);           // t = s+1, exact in fp32
    const float t1 = (float)(s0 + 257);

    float acc0 = 0.0f, acc1 = 0.0f;
#pragma unroll
    for (int i = 0; i < 8; ++i) {
        const float wr[4] = { wv[i].x, wv[i].y, wv[i].z, wv[i].w };
        const float ar[4] = { av[i].x, av[i].y, av[i].z, av[i].w };
#pragma unroll
        for (int j = 0; j < 4; ++j) {
            float r0 = wr[j] * t0;
            float r1 = wr[j] * t1;
            acc0 = fmaf(ar[j], __builtin_amdgcn_sinf(__builtin_amdgcn_fractf(r0)), acc0);
            acc1 = fmaf(ar[j], __builtin_amdgcn_sinf(__builtin_amdgcn_fractf(r1)), acc1);
        }
    }

    float* op = out + pair * N_SMP + s0;
    op[0]   = acc0;
    op[256] = acc1;

    // block max of |acc| -> one plain store per block
    float av_ = fmaxf(fabsf(acc0), fabsf(acc1));
#pragma unroll
    for (int m = 32; m >= 1; m >>= 1)
        av_ = fmaxf(av_, __shfl_xor(av_, m, 64));
    __shared__ float wm[4];
    if ((tid & 63) == 0) wm[tid >> 6] = av_;
    __syncthreads();
    if (tid == 0)
        bmax[pair * 64 + blk] = fmaxf(fmaxf(wm[0], wm[1]), fmaxf(wm[2], wm[3]));
}

// ---------------------------------------------------------------------------
// Kernel 3: reduce the 64 per-block maxes, then normalize (float4).
// ---------------------------------------------------------------------------
__global__ __launch_bounds__(256) void f0res_norm(
    float* __restrict__ out, const float* __restrict__ bmax)
{
    const int pair = blockIdx.x >> 5;                   // 32 blocks per pair
    const int tid  = threadIdx.x;

    float v = 0.0f;
    if (tid < 64) v = bmax[pair * 64 + tid];
#pragma unroll
    for (int m = 32; m >= 1; m >>= 1)
        v = fmaxf(v, __shfl_xor(v, m, 64));
    __shared__ float wm[4];
    if ((tid & 63) == 0) wm[tid >> 6] = v;              // waves 1-3 write 0 (harmless)
    __syncthreads();
    const float mx  = fmaxf(fmaxf(wm[0], wm[1]), fmaxf(wm[2], wm[3])) + 1e-8f;
    const float inv = 1.0f / mx;

    const int idx = ((blockIdx.x & 31) << 8) + tid;     // 256 float4 per block
    float4* o4 = (float4*)(out + pair * N_SMP);
    float4 val = o4[idx];
    val.x *= inv; val.y *= inv; val.z *= inv; val.w *= inv;
    o4[idx] = val;
}

extern "C" void kernel_launch(void* const* d_in, const int* in_sizes, int n_in,
                              void* d_out, int out_size, void* d_ws, size_t ws_size,
                              hipStream_t stream) {
    const float* f0  = (const float*)d_in[0];
    const float* dec = (const float*)d_in[1];
    const float* fs  = (const float*)d_in[2];
    float* out = (float*)d_out;

    float* w    = (float*)d_ws;                 // 64*32 floats (revolutions)
    float* a    = w + N_PAIR * N_OCT;           // 64*32 floats
    float* bmax = a + N_PAIR * N_OCT;           // 64*64 floats

    f0res_setup<<<1, 64, 0, stream>>>(f0, dec, fs, w, a);
    f0res_osc<<<N_PAIR * 64, 256, 0, stream>>>(w, a, out, bmax);
    f0res_norm<<<N_PAIR * 32, 256, 0, stream>>>(out, bmax);
}